// Round 12
// baseline (726.187 us; speedup 1.0000x reference)
//
#include <hip/hip_runtime.h>
#include <math.h>

#define N_NODES 20000
#define N_EDGES 160000
#define N_CFG   1000
#define OP_FEAT 140
#define CFG_FEAT 24
#define HID     256
#define EMB     128
#define E_TOT   (N_EDGES + N_NODES)
#define K288    288          // 268 and 280 padded to multiple of 32
#define MPAD    20096        // 157 * 128
#define NW      512          // fused Wl|Wr output width

typedef __attribute__((ext_vector_type(8))) short short8v;
typedef __attribute__((ext_vector_type(4))) float f32x4;

__device__ __forceinline__ short f2bf(float f) {
  unsigned u = __float_as_uint(f);
  unsigned r = (u + 0x7FFFu + ((u >> 16) & 1u)) >> 16;
  return (short)r;
}
__device__ __forceinline__ float bf2f(short s) {
  return __uint_as_float(((unsigned)(unsigned short)s) << 16);
}
__device__ __forceinline__ float gelu_f(float x) {
  return 0.5f * x * (1.0f + erff(x * 0.70710678118654752f));
}

#define GLOAD_LDS(gptr, lptr) __builtin_amdgcn_global_load_lds( \
    (const __attribute__((address_space(1))) void*)(gptr),      \
    (__attribute__((address_space(3))) void*)(lptr), 16, 0, 0)

// ---------------------------------------------------------------- weight prep (merged)
__global__ void prep_weights(
    const float* __restrict__ eW1, const float* __restrict__ eW2,
    const float* __restrict__ lW1, const float* __restrict__ lW2,
    const float* __restrict__ Wl, const float* __restrict__ Wr,
    const float* __restrict__ bl, const float* __restrict__ br,
    short* __restrict__ W1t, short* __restrict__ W2t,
    short* __restrict__ lW1t, short* __restrict__ lW2t,
    short* __restrict__ Wlrt, float* __restrict__ blr)
{
  int i = blockIdx.x * 256 + threadIdx.x;
  const int s1 = HID * K288;      // W1t  [256][288]
  const int s2 = HID * HID;       // W2t  [256][256]
  const int s3 = HID * K288;      // lW1t [256][288]
  const int s4 = 128 * HID;       // lW2t [128][256]
  const int s5 = 4 * NW * HID;    // Wlrt [4][512][256]
  const int s6 = 4 * NW;          // blr
  if (i < s1) { int n = i / K288, k = i % K288;
    W1t[i] = (k < EMB + OP_FEAT) ? f2bf(eW1[(size_t)k * HID + n]) : (short)0; return; }
  i -= s1;
  if (i < s2) { int n = i >> 8, k = i & 255;
    W2t[i] = f2bf(eW2[(size_t)k * HID + n]); return; }
  i -= s2;
  if (i < s3) { int n = i / K288, k = i % K288;
    lW1t[i] = (k < CFG_FEAT + HID) ? f2bf(lW1[(size_t)k * HID + n]) : (short)0; return; }
  i -= s3;
  if (i < s4) { int n = i >> 8, k = i & 255;
    lW2t[i] = f2bf(lW2[(size_t)k * 128 + n]); return; }
  i -= s4;
  if (i < s5) { int l = i >> 17, rem = i & 131071, n = rem >> 8, k = rem & 255;
    float v = (n < HID) ? Wl[(size_t)l * HID * HID + (size_t)k * HID + n]
                        : Wr[(size_t)l * HID * HID + (size_t)k * HID + (n - HID)];
    Wlrt[i] = f2bf(v); return; }
  i -= s5;
  if (i < s6) { int l = i >> 9, j = i & 511;
    blr[i] = (j < HID) ? bl[l * HID + j] : br[l * HID + j - HID]; }
}

// ---------------------------------------------------------------- prep
__global__ __launch_bounds__(256) void prep_kernel(
    const float* __restrict__ node_feat, const float* __restrict__ nf_mean,
    const float* __restrict__ nf_std, const float* __restrict__ emb_table,
    const int* __restrict__ opcode, short* __restrict__ x268b)
{
  int wave = threadIdx.x >> 6;
  int lane = threadIdx.x & 63;
  int row = blockIdx.x * 4 + wave;
  if (row >= N_NODES) return;
  int op = opcode[row];
  float t0 = emb_table[op * EMB + lane];
  float t1 = emb_table[op * EMB + 64 + lane];
  float ss = t0 * t0 + t1 * t1;
  #pragma unroll
  for (int off = 32; off; off >>= 1) ss += __shfl_xor(ss, off);
  float sc = fminf(1.0f, 1.0f / (sqrtf(ss) + 1e-7f));
  short* dst = x268b + (size_t)row * K288;
  dst[lane] = f2bf(t0 * sc);
  dst[64 + lane] = f2bf(t1 * sc);
  for (int k = lane; k < OP_FEAT; k += 64)
    dst[EMB + k] = f2bf((node_feat[(size_t)row * OP_FEAT + k] - nf_mean[k]) / (nf_std[k] + 1e-4f));
  if (lane < K288 - EMB - OP_FEAT) dst[EMB + OP_FEAT + lane] = 0;
}

// ---------------------------------------------------------------- MFMA GEMM (2-phase, BK=32)
template<int BM, int BN>
__global__ __launch_bounds__(256) void gemm_mfma(
    const short* __restrict__ A, const short* __restrict__ Wt,
    const float* __restrict__ bias, float* __restrict__ C,
    short* __restrict__ Cb, float* __restrict__ stats,
    int M, int N, int Kpad)
{
  constexpr int MI = (BM == 128) ? 4 : 2;
  constexpr int NI = (BN == 128) ? 4 : 2;
  __shared__ __align__(16) short As[2][4][BM][8];
  __shared__ __align__(16) short Bs[2][4][BN][8];
  int tid = threadIdx.x;
  int wave = tid >> 6, lane = tid & 63;
  int bm = blockIdx.x * BM, bn = blockIdx.y * BN;
  int wr = (BM == 128) ? (wave >> 1) * 64 : (wave >> 1) * 32;
  int wc = (BM == 128) ? (wave & 1) * 64 : (wave & 1) * 32;
  int g = lane >> 4, r16 = lane & 15;
  f32x4 acc[MI][NI] = {};
  int nt = Kpad >> 5;

  auto STAGE = [&](int t, int b) {
    int k0 = t * 32;
    if constexpr (BM == 128) {
      #pragma unroll
      for (int s2 = 0; s2 < 2; s2++) {
        int s = wave * 2 + s2;
        int sg = s >> 1, r0 = (s & 1) * 64;
        GLOAD_LDS(A  + (size_t)(bm + r0 + lane) * Kpad + k0 + sg * 8, &As[b][sg][r0][0]);
        GLOAD_LDS(Wt + (size_t)(bn + r0 + lane) * Kpad + k0 + sg * 8, &Bs[b][sg][r0][0]);
      }
    } else {
      GLOAD_LDS(A  + (size_t)(bm + lane) * Kpad + k0 + wave * 8, &As[b][wave][0][0]);
      GLOAD_LDS(Wt + (size_t)(bn + lane) * Kpad + k0 + wave * 8, &Bs[b][wave][0][0]);
    }
  };

  STAGE(0, 0);
  for (int t = 0; t < nt; t++) {
    int b = t & 1;
    __syncthreads();
    if (t + 1 < nt) STAGE(t + 1, b ^ 1);
    short8v af[MI], bfv[NI];
    #pragma unroll
    for (int mi = 0; mi < MI; mi++)
      af[mi] = *(const short8v*)&As[b][g][wr + mi * 16 + r16][0];
    #pragma unroll
    for (int ni = 0; ni < NI; ni++)
      bfv[ni] = *(const short8v*)&Bs[b][g][wc + ni * 16 + r16][0];
    #pragma unroll
    for (int mi = 0; mi < MI; mi++)
      #pragma unroll
      for (int ni = 0; ni < NI; ni++)
        acc[mi][ni] = __builtin_amdgcn_mfma_f32_16x16x32_bf16(af[mi], bfv[ni], acc[mi][ni], 0, 0, 0);
  }

  int rg = lane >> 4;
  #pragma unroll
  for (int ni = 0; ni < NI; ni++) {
    int gc = bn + wc + ni * 16 + r16;
    float bv = bias ? bias[gc] : 0.f;
    float s = 0.f, sq = 0.f;
    #pragma unroll
    for (int mi = 0; mi < MI; mi++) {
      #pragma unroll
      for (int r = 0; r < 4; r++) {
        int gr = bm + wr + mi * 16 + rg * 4 + r;
        if (gr < M) {
          float v = acc[mi][ni][r] + bv;
          if (C)  C[(size_t)gr * N + gc] = v;
          if (Cb) Cb[(size_t)gr * N + gc] = f2bf(v);
          s += v; sq += v * v;
        }
      }
    }
    if (stats) {
      s  += __shfl_xor(s, 16);  sq += __shfl_xor(sq, 16);
      s  += __shfl_xor(s, 32);  sq += __shfl_xor(sq, 32);
      if (rg == 0) { atomicAdd(&stats[gc], s); atomicAdd(&stats[N + gc], sq); }
    }
  }
}

// ---------------------------------------------------------------- norm + gelu (column-major)
__global__ void norm_gelu_col(const float* __restrict__ X, short* __restrict__ Yb,
                              int M, int C, const float* __restrict__ stats,
                              float* __restrict__ psum, unsigned* __restrict__ pmax)
{
  int c = threadIdx.x;
  int r0 = blockIdx.x * 32, r1 = min(r0 + 32, M);
  float invM = 1.0f / (float)M;
  float mean = stats[c] * invM;
  float var = stats[C + c] * invM - mean * mean;
  float inv = rsqrtf(var + 1e-5f);
  float s = 0.f, mx = -INFINITY;
  for (int r = r0; r < r1; r++) {
    float y = gelu_f((X[(size_t)r * C + c] - mean) * inv);
    Yb[(size_t)r * C + c] = f2bf(y);
    s += y; mx = fmaxf(mx, y);
  }
  if (psum) {
    unsigned b = __float_as_uint(mx);
    unsigned enc = (b & 0x80000000u) ? ~b : (b | 0x80000000u);
    atomicAdd(&psum[c], s);
    atomicMax(&pmax[c], enc);
  }
}

// ---------------------------------------------------------------- CSR build
__global__ void edge_count(const int* __restrict__ ei, int* __restrict__ counts) {
  int e = blockIdx.x * blockDim.x + threadIdx.x;
  if (e >= E_TOT) return;
  int dst = (e < N_EDGES) ? ei[N_EDGES + e] : (e - N_EDGES);
  atomicAdd(&counts[dst], 1);
}

__global__ __launch_bounds__(1024) void scan_kernel(const int* __restrict__ counts,
                                                    int* __restrict__ indptr)
{
  __shared__ int sh[1024];
  int t = threadIdx.x;
  const int chunk = (N_NODES + 1023) / 1024;
  int start = t * chunk, end = min(start + chunk, N_NODES);
  int sum = 0;
  for (int i = start; i < end; i++) sum += counts[i];
  sh[t] = sum;
  __syncthreads();
  for (int off = 1; off < 1024; off <<= 1) {
    int v = (t >= off) ? sh[t - off] : 0;
    __syncthreads();
    sh[t] += v;
    __syncthreads();
  }
  int run = (t > 0) ? sh[t - 1] : 0;
  for (int i = start; i < end; i++) { indptr[i] = run; run += counts[i]; }
  if (t == 1023) indptr[N_NODES] = run;
}

__global__ void edge_fill(const int* __restrict__ ei, const int* __restrict__ indptr,
                          int* __restrict__ cursor, int* __restrict__ col)
{
  int e = blockIdx.x * blockDim.x + threadIdx.x;
  if (e >= E_TOT) return;
  int src, dst;
  if (e < N_EDGES) { src = ei[e]; dst = ei[N_EDGES + e]; }
  else             { src = dst = e - N_EDGES; }
  int pos = indptr[dst] + atomicAdd(&cursor[dst], 1);
  col[pos] = src;
}

// ---------------------------------------------------------------- GAT aggregation
// xlr bf16 [N,512]=[xl|xr]. TWO nodes per wave (half-waves of 32 lanes,
// 8 ch/lane, short8 16B gathers, 5-level reduce). 4 edges per online-softmax
// step, branch-free pad via col[e0]; shorter half pads with p=-INF (w=0 no-op;
// iter 0 always valid via self-loop). Column stats fused: LDS atomics
// (<=8 writers/addr, 256-thr blocks) + 1 global atomic per channel per block.
// All arrays statically indexed (rule #20).
__global__ __launch_bounds__(256) void gat_agg(
    const short* __restrict__ xlr,
    const int* __restrict__ indptr, const int* __restrict__ col,
    const float* __restrict__ att, const float* __restrict__ bias,
    float* __restrict__ out, float* __restrict__ stats)
{
  __shared__ float sums[HID];
  __shared__ float sqs[HID];
  int tid = threadIdx.x;
  if (tid < HID) { sums[tid] = 0.f; sqs[tid] = 0.f; }
  __syncthreads();
  int wave = tid >> 6, lane = tid & 63;
  int hw = lane >> 5, ln = lane & 31;
  int node = blockIdx.x * 8 + wave * 2 + hw;   // N_NODES = 2500*8 exactly
  float attc[8], xri[8], o[8] = {0, 0, 0, 0, 0, 0, 0, 0};
  {
    short8v xr8 = *(const short8v*)(xlr + (size_t)node * NW + HID + ln * 8);
    #pragma unroll
    for (int k = 0; k < 8; k++) {
      attc[k] = att[ln * 8 + k];
      xri[k] = bf2f(xr8[k]);
    }
  }
  int e0 = indptr[node], e1 = indptr[node + 1];
  int deg = e1 - e0;
  int dother = __shfl_xor(deg, 32);
  int iters = (max(deg, dother) + 3) >> 2;
  float m = -INFINITY, s = 0.f;
  for (int it = 0; it < iters; it++) {
    int base = e0 + it * 4;
    float p[4];
    float xlj[4][8];
    #pragma unroll
    for (int b = 0; b < 4; b++) {
      bool valid = (base + b) < e1;             // uniform within half-wave
      int j = col[valid ? base + b : e0];       // e0 always valid (self-loop)
      short8v v8 = *(const short8v*)(xlr + (size_t)j * NW + ln * 8);
      float pp = 0.f;
      #pragma unroll
      for (int k = 0; k < 8; k++) {
        xlj[b][k] = bf2f(v8[k]);
        float h = xlj[b][k] + xri[k];
        float lr = h > 0.f ? h : 0.2f * h;
        pp += lr * attc[k];
      }
      p[b] = valid ? pp : -INFINITY;
    }
    // 4 interleaved 32-lane reductions (xor<32 stays within half-wave)
    #pragma unroll
    for (int off = 16; off; off >>= 1) {
      #pragma unroll
      for (int b = 0; b < 4; b++) p[b] += __shfl_xor(p[b], off);
    }
    float mn = fmaxf(m, fmaxf(fmaxf(p[0], p[1]), fmaxf(p[2], p[3])));
    float scale = __expf(m - mn);
    float w[4];
    #pragma unroll
    for (int b = 0; b < 4; b++) w[b] = __expf(p[b] - mn);   // pad -> 0
    s = s * scale + w[0] + w[1] + w[2] + w[3];
    #pragma unroll
    for (int k = 0; k < 8; k++)
      o[k] = o[k] * scale + w[0] * xlj[0][k] + w[1] * xlj[1][k]
                          + w[2] * xlj[2][k] + w[3] * xlj[3][k];
    m = mn;
  }
  float inv = 1.0f / (s + 1e-16f);
  f32x4 ov0, ov1;
  #pragma unroll
  for (int k = 0; k < 8; k++) {
    float v = o[k] * inv + bias[ln * 8 + k];
    if (k < 4) ov0[k] = v; else ov1[k - 4] = v;
    atomicAdd(&sums[ln * 8 + k], v);
    atomicAdd(&sqs[ln * 8 + k], v * v);
  }
  *(f32x4*)(out + (size_t)node * HID + ln * 8) = ov0;
  *(f32x4*)(out + (size_t)node * HID + ln * 8 + 4) = ov1;
  __syncthreads();
  if (tid < HID) {
    atomicAdd(&stats[tid], sums[tid]);
    atomicAdd(&stats[HID + tid], sqs[tid]);
  }
}

// ---------------------------------------------------------------- late stage
__device__ __forceinline__ float fdec(unsigned u) {
  unsigned b = (u & 0x80000000u) ? (u & 0x7FFFFFFFu) : ~u;
  return __uint_as_float(b);
}

__global__ void build_xlate(const float* __restrict__ cfg, const float* __restrict__ cmean,
                            const float* __restrict__ cstd, const float* __restrict__ psum,
                            const unsigned* __restrict__ pmax, short* __restrict__ xlateb)
{
  int i = blockIdx.x * blockDim.x + threadIdx.x;
  if (i >= N_CFG * K288) return;
  int r = i / K288, c = i % K288;
  float v;
  if (c < CFG_FEAT) v = (cfg[r * CFG_FEAT + c] - cmean[c]) / (cstd[c] + 1e-4f);
  else if (c < CFG_FEAT + HID) {
    int p = c - CFG_FEAT;
    v = psum[p] * (1.0f / N_NODES) + fdec(pmax[p]);
  } else v = 0.f;
  xlateb[i] = f2bf(v);
}

// pred with fused final norm+gelu (stats from L2 GEMM epilogue)
__global__ __launch_bounds__(64) void pred_kernel(
    const float* __restrict__ h2, const float* __restrict__ stats,
    const float* __restrict__ W, const float* __restrict__ b,
    float* __restrict__ out)
{
  int r = blockIdx.x, lane = threadIdx.x;
  const float invM = 1.0f / (float)N_CFG;
  float v = 0.f;
  #pragma unroll
  for (int t = 0; t < 2; t++) {
    int c = lane + 64 * t;
    float mean = stats[c] * invM;
    float var = stats[128 + c] * invM - mean * mean;
    float y = gelu_f((h2[(size_t)r * 128 + c] - mean) * rsqrtf(var + 1e-5f));
    v += y * W[c];
  }
  #pragma unroll
  for (int off = 32; off; off >>= 1) v += __shfl_xor(v, off);
  if (lane == 0) out[r] = v + b[0];
}

// ================================================================ launch
extern "C" void kernel_launch(void* const* d_in, const int* in_sizes, int n_in,
                              void* d_out, int out_size, void* d_ws, size_t ws_size,
                              hipStream_t stream)
{
  const float* node_feat   = (const float*)d_in[0];
  const float* config_feat = (const float*)d_in[1];
  const float* nf_mean     = (const float*)d_in[2];
  const float* nf_std      = (const float*)d_in[3];
  const float* cf_mean     = (const float*)d_in[4];
  const float* cf_std      = (const float*)d_in[5];
  const float* emb_table   = (const float*)d_in[6];
  const float* early_W1    = (const float*)d_in[7];
  const float* early_W2    = (const float*)d_in[8];
  const float* gat_Wl      = (const float*)d_in[9];
  const float* gat_bl      = (const float*)d_in[10];
  const float* gat_Wr      = (const float*)d_in[11];
  const float* gat_br      = (const float*)d_in[12];
  const float* gat_att     = (const float*)d_in[13];
  const float* gat_bias    = (const float*)d_in[14];
  const float* late_W1     = (const float*)d_in[15];
  const float* late_W2     = (const float*)d_in[16];
  const float* pred_W      = (const float*)d_in[17];
  const float* pred_b      = (const float*)d_in[18];
  const int*   node_opcode = (const int*)d_in[19];
  const int*   edge_index  = (const int*)d_in[20];
  float* out = (float*)d_out;
  (void)in_sizes; (void)n_in; (void)out_size; (void)ws_size;

  char* ws = (char*)d_ws;
  size_t off = 0;
  auto alloc = [&](size_t bytes) -> void* {
    void* p = ws + off;
    off += (bytes + 255) & ~255ull;
    return p;
  };
  short* x268b = (short*)alloc((size_t)MPAD * K288 * 2);
  float* bufB  = (float*)alloc((size_t)N_NODES * HID * 4);
  short* bufAb = (short*)alloc((size_t)MPAD * HID * 2);
  short* xlr   = (short*)alloc((size_t)N_NODES * NW * 2);
  int* indptr  = (int*)alloc((N_NODES + 1) * 4);
  int* colidx  = (int*)alloc((size_t)E_TOT * 4);
  short* xlateb = (short*)alloc((size_t)1024 * K288 * 2);
  float* h1    = (float*)alloc((size_t)N_CFG * HID * 4);
  short* h1b   = (short*)alloc((size_t)1024 * HID * 2);
  float* h2    = (float*)alloc((size_t)N_CFG * 128 * 4);
  short* W1t   = (short*)alloc((size_t)HID * K288 * 2);
  short* W2t   = (short*)alloc((size_t)HID * HID * 2);
  short* Wlrt  = (short*)alloc((size_t)4 * NW * HID * 2);
  float* blr   = (float*)alloc(4 * NW * 4);
  short* lW1t  = (short*)alloc((size_t)HID * K288 * 2);
  short* lW2t  = (short*)alloc((size_t)128 * HID * 2);

  // ---- contiguous zero region (single memset per call) ----
  float* zbase = (float*)alloc((8 * 1024 + 512 + 2 * N_NODES) * 4);
  float* stats8 = zbase;
  float* psum   = zbase + 8192;
  unsigned* pmax = (unsigned*)(zbase + 8192 + 256);
  int* counts   = (int*)(zbase + 8192 + 512);
  int* cursor   = counts + N_NODES;
  const size_t zbytes = (8 * 1024 + 512 + 2 * N_NODES) * 4;
  auto slot = [&](int s) { return stats8 + s * 1024; };
  // slots: 0=E1 1=E2 2..5=G0..G3 6=L1 7=L2

  auto run_gemm = [&](int BM, const short* A, const short* Wt, const float* bias, float* C,
                      short* Cb, float* stats, int M, int N, int Kpad) {
    if (BM == 128) {
      dim3 grid((M + 127) / 128, N / 128);
      hipLaunchKernelGGL((gemm_mfma<128, 128>), grid, dim3(256), 0, stream,
                         A, Wt, bias, C, Cb, stats, M, N, Kpad);
    } else {
      dim3 grid((M + 63) / 64, N / 64);
      hipLaunchKernelGGL((gemm_mfma<64, 64>), grid, dim3(256), 0, stream,
                         A, Wt, bias, C, Cb, stats, M, N, Kpad);
    }
  };
  auto run_norm = [&](const float* X, short* Yb, int M, int C, float* stats,
                      float* ps, unsigned* pm) {
    hipLaunchKernelGGL(norm_gelu_col, dim3((M + 31) / 32), dim3(C), 0, stream,
                       X, Yb, M, C, stats, ps, pm);
  };

  hipMemsetAsync(zbase, 0, zbytes, stream);

  // weight prep (one kernel)
  {
    int total = HID * K288 + HID * HID + HID * K288 + 128 * HID + 4 * NW * HID + 4 * NW;
    hipLaunchKernelGGL(prep_weights, dim3((total + 255) / 256), dim3(256), 0, stream,
                       early_W1, early_W2, late_W1, late_W2, gat_Wl, gat_Wr, gat_bl, gat_br,
                       W1t, W2t, lW1t, lW2t, Wlrt, blr);
  }

  // CSR build
  hipLaunchKernelGGL(edge_count, dim3((E_TOT + 255) / 256), dim3(256), 0, stream,
                     edge_index, counts);
  hipLaunchKernelGGL(scan_kernel, dim3(1), dim3(1024), 0, stream, counts, indptr);
  hipLaunchKernelGGL(edge_fill, dim3((E_TOT + 255) / 256), dim3(256), 0, stream,
                     edge_index, indptr, cursor, colidx);

  // prep + early MLP
  hipLaunchKernelGGL(prep_kernel, dim3((N_NODES + 3) / 4), dim3(256), 0, stream,
                     node_feat, nf_mean, nf_std, emb_table, node_opcode, x268b);
  run_gemm(64, x268b, W1t, nullptr, bufB, nullptr, slot(0), N_NODES, HID, K288);
  run_norm(bufB, bufAb, N_NODES, HID, slot(0), nullptr, nullptr);
  run_gemm(64, bufAb, W2t, nullptr, bufB, nullptr, slot(1), N_NODES, HID, HID);
  run_norm(bufB, bufAb, N_NODES, HID, slot(1), nullptr, nullptr);

  // 4 GAT layers (colstats fused into gat_agg)
  for (int l = 0; l < 4; l++) {
    run_gemm(128, bufAb, Wlrt + (size_t)l * NW * HID, blr + l * NW, nullptr, xlr, nullptr,
             N_NODES, NW, HID);
    hipLaunchKernelGGL(gat_agg, dim3(N_NODES / 8), dim3(256), 0, stream,
                       xlr, indptr, colidx, gat_att + l * HID, gat_bias + l * HID,
                       bufB, slot(2 + l));
    run_norm(bufB, bufAb, N_NODES, HID, slot(2 + l),
             (l == 3) ? psum : nullptr, (l == 3) ? pmax : nullptr);
  }

  // late MLP
  hipLaunchKernelGGL(build_xlate, dim3((N_CFG * K288 + 255) / 256), dim3(256), 0, stream,
                     config_feat, cf_mean, cf_std, psum, pmax, xlateb);
  run_gemm(64, xlateb, lW1t, nullptr, h1, nullptr, slot(6), N_CFG, HID, K288);
  run_norm(h1, h1b, N_CFG, HID, slot(6), nullptr, nullptr);
  run_gemm(64, h1b, lW2t, nullptr, h2, nullptr, slot(7), N_CFG, 128, HID);
  hipLaunchKernelGGL(pred_kernel, dim3(N_CFG), dim3(64), 0, stream,
                     h2, slot(7), pred_W, pred_b, out);
}

// Round 13
// 588.179 us; speedup vs baseline: 1.2346x; 1.2346x over previous
//
#include <hip/hip_runtime.h>
#include <math.h>

#define N_NODES 20000
#define N_EDGES 160000
#define N_CFG   1000
#define OP_FEAT 140
#define CFG_FEAT 24
#define HID     256
#define EMB     128
#define E_TOT   (N_EDGES + N_NODES)
#define K288    288          // 268 and 280 padded to multiple of 32
#define MPAD    20096        // 157 * 128
#define NW      512          // fused Wl|Wr output width

typedef __attribute__((ext_vector_type(8))) short short8v;
typedef __attribute__((ext_vector_type(4))) float f32x4;

__device__ __forceinline__ short f2bf(float f) {
  unsigned u = __float_as_uint(f);
  unsigned r = (u + 0x7FFFu + ((u >> 16) & 1u)) >> 16;
  return (short)r;
}
__device__ __forceinline__ float bf2f(short s) {
  return __uint_as_float(((unsigned)(unsigned short)s) << 16);
}
__device__ __forceinline__ float gelu_f(float x) {
  return 0.5f * x * (1.0f + erff(x * 0.70710678118654752f));
}

#define GLOAD_LDS(gptr, lptr) __builtin_amdgcn_global_load_lds( \
    (const __attribute__((address_space(1))) void*)(gptr),      \
    (__attribute__((address_space(3))) void*)(lptr), 16, 0, 0)

// ---------------------------------------------------------------- weight prep (merged)
__global__ void prep_weights(
    const float* __restrict__ eW1, const float* __restrict__ eW2,
    const float* __restrict__ lW1, const float* __restrict__ lW2,
    const float* __restrict__ Wl, const float* __restrict__ Wr,
    const float* __restrict__ bl, const float* __restrict__ br,
    short* __restrict__ W1t, short* __restrict__ W2t,
    short* __restrict__ lW1t, short* __restrict__ lW2t,
    short* __restrict__ Wlrt, float* __restrict__ blr)
{
  int i = blockIdx.x * 256 + threadIdx.x;
  const int s1 = HID * K288;      // W1t  [256][288]
  const int s2 = HID * HID;       // W2t  [256][256]
  const int s3 = HID * K288;      // lW1t [256][288]
  const int s4 = 128 * HID;       // lW2t [128][256]
  const int s5 = 4 * NW * HID;    // Wlrt [4][512][256]
  const int s6 = 4 * NW;          // blr
  if (i < s1) { int n = i / K288, k = i % K288;
    W1t[i] = (k < EMB + OP_FEAT) ? f2bf(eW1[(size_t)k * HID + n]) : (short)0; return; }
  i -= s1;
  if (i < s2) { int n = i >> 8, k = i & 255;
    W2t[i] = f2bf(eW2[(size_t)k * HID + n]); return; }
  i -= s2;
  if (i < s3) { int n = i / K288, k = i % K288;
    lW1t[i] = (k < CFG_FEAT + HID) ? f2bf(lW1[(size_t)k * HID + n]) : (short)0; return; }
  i -= s3;
  if (i < s4) { int n = i >> 8, k = i & 255;
    lW2t[i] = f2bf(lW2[(size_t)k * 128 + n]); return; }
  i -= s4;
  if (i < s5) { int l = i >> 17, rem = i & 131071, n = rem >> 8, k = rem & 255;
    float v = (n < HID) ? Wl[(size_t)l * HID * HID + (size_t)k * HID + n]
                        : Wr[(size_t)l * HID * HID + (size_t)k * HID + (n - HID)];
    Wlrt[i] = f2bf(v); return; }
  i -= s5;
  if (i < s6) { int l = i >> 9, j = i & 511;
    blr[i] = (j < HID) ? bl[l * HID + j] : br[l * HID + j - HID]; }
}

// ---------------------------------------------------------------- prep
__global__ __launch_bounds__(256) void prep_kernel(
    const float* __restrict__ node_feat, const float* __restrict__ nf_mean,
    const float* __restrict__ nf_std, const float* __restrict__ emb_table,
    const int* __restrict__ opcode, short* __restrict__ x268b)
{
  int wave = threadIdx.x >> 6;
  int lane = threadIdx.x & 63;
  int row = blockIdx.x * 4 + wave;
  if (row >= N_NODES) return;
  int op = opcode[row];
  float t0 = emb_table[op * EMB + lane];
  float t1 = emb_table[op * EMB + 64 + lane];
  float ss = t0 * t0 + t1 * t1;
  #pragma unroll
  for (int off = 32; off; off >>= 1) ss += __shfl_xor(ss, off);
  float sc = fminf(1.0f, 1.0f / (sqrtf(ss) + 1e-7f));
  short* dst = x268b + (size_t)row * K288;
  dst[lane] = f2bf(t0 * sc);
  dst[64 + lane] = f2bf(t1 * sc);
  for (int k = lane; k < OP_FEAT; k += 64)
    dst[EMB + k] = f2bf((node_feat[(size_t)row * OP_FEAT + k] - nf_mean[k]) / (nf_std[k] + 1e-4f));
  if (lane < K288 - EMB - OP_FEAT) dst[EMB + OP_FEAT + lane] = 0;
}

// ---------------------------------------------------------------- MFMA GEMM (2-phase, BK=32)
template<int BM, int BN>
__global__ __launch_bounds__(256) void gemm_mfma(
    const short* __restrict__ A, const short* __restrict__ Wt,
    const float* __restrict__ bias, float* __restrict__ C,
    short* __restrict__ Cb, float* __restrict__ stats,
    int M, int N, int Kpad)
{
  constexpr int MI = (BM == 128) ? 4 : 2;
  constexpr int NI = (BN == 128) ? 4 : 2;
  __shared__ __align__(16) short As[2][4][BM][8];
  __shared__ __align__(16) short Bs[2][4][BN][8];
  int tid = threadIdx.x;
  int wave = tid >> 6, lane = tid & 63;
  int bm = blockIdx.x * BM, bn = blockIdx.y * BN;
  int wr = (BM == 128) ? (wave >> 1) * 64 : (wave >> 1) * 32;
  int wc = (BM == 128) ? (wave & 1) * 64 : (wave & 1) * 32;
  int g = lane >> 4, r16 = lane & 15;
  f32x4 acc[MI][NI] = {};
  int nt = Kpad >> 5;

  auto STAGE = [&](int t, int b) {
    int k0 = t * 32;
    if constexpr (BM == 128) {
      #pragma unroll
      for (int s2 = 0; s2 < 2; s2++) {
        int s = wave * 2 + s2;
        int sg = s >> 1, r0 = (s & 1) * 64;
        GLOAD_LDS(A  + (size_t)(bm + r0 + lane) * Kpad + k0 + sg * 8, &As[b][sg][r0][0]);
        GLOAD_LDS(Wt + (size_t)(bn + r0 + lane) * Kpad + k0 + sg * 8, &Bs[b][sg][r0][0]);
      }
    } else {
      GLOAD_LDS(A  + (size_t)(bm + lane) * Kpad + k0 + wave * 8, &As[b][wave][0][0]);
      GLOAD_LDS(Wt + (size_t)(bn + lane) * Kpad + k0 + wave * 8, &Bs[b][wave][0][0]);
    }
  };

  STAGE(0, 0);
  for (int t = 0; t < nt; t++) {
    int b = t & 1;
    __syncthreads();
    if (t + 1 < nt) STAGE(t + 1, b ^ 1);
    short8v af[MI], bfv[NI];
    #pragma unroll
    for (int mi = 0; mi < MI; mi++)
      af[mi] = *(const short8v*)&As[b][g][wr + mi * 16 + r16][0];
    #pragma unroll
    for (int ni = 0; ni < NI; ni++)
      bfv[ni] = *(const short8v*)&Bs[b][g][wc + ni * 16 + r16][0];
    #pragma unroll
    for (int mi = 0; mi < MI; mi++)
      #pragma unroll
      for (int ni = 0; ni < NI; ni++)
        acc[mi][ni] = __builtin_amdgcn_mfma_f32_16x16x32_bf16(af[mi], bfv[ni], acc[mi][ni], 0, 0, 0);
  }

  int rg = lane >> 4;
  #pragma unroll
  for (int ni = 0; ni < NI; ni++) {
    int gc = bn + wc + ni * 16 + r16;
    float bv = bias ? bias[gc] : 0.f;
    float s = 0.f, sq = 0.f;
    #pragma unroll
    for (int mi = 0; mi < MI; mi++) {
      #pragma unroll
      for (int r = 0; r < 4; r++) {
        int gr = bm + wr + mi * 16 + rg * 4 + r;
        if (gr < M) {
          float v = acc[mi][ni][r] + bv;
          if (C)  C[(size_t)gr * N + gc] = v;
          if (Cb) Cb[(size_t)gr * N + gc] = f2bf(v);
          s += v; sq += v * v;
        }
      }
    }
    if (stats) {
      s  += __shfl_xor(s, 16);  sq += __shfl_xor(sq, 16);
      s  += __shfl_xor(s, 32);  sq += __shfl_xor(sq, 32);
      if (rg == 0) { atomicAdd(&stats[gc], s); atomicAdd(&stats[N + gc], sq); }
    }
  }
}

// ---------------------------------------------------------------- column stats
__global__ void colstats(const float* __restrict__ X, int M, int C,
                         float* __restrict__ stats)
{
  int c = threadIdx.x;
  int r0 = blockIdx.x * 64;
  int r1 = min(r0 + 64, M);
  float s = 0.f, sq = 0.f;
  for (int r = r0; r < r1; r++) {
    float v = X[(size_t)r * C + c];
    s += v; sq += v * v;
  }
  atomicAdd(&stats[c], s);
  atomicAdd(&stats[C + c], sq);
}

// ---------------------------------------------------------------- norm + gelu (column-major)
__global__ void norm_gelu_col(const float* __restrict__ X, short* __restrict__ Yb,
                              int M, int C, const float* __restrict__ stats,
                              float* __restrict__ psum, unsigned* __restrict__ pmax)
{
  int c = threadIdx.x;
  int r0 = blockIdx.x * 32, r1 = min(r0 + 32, M);
  float invM = 1.0f / (float)M;
  float mean = stats[c] * invM;
  float var = stats[C + c] * invM - mean * mean;
  float inv = rsqrtf(var + 1e-5f);
  float s = 0.f, mx = -INFINITY;
  for (int r = r0; r < r1; r++) {
    float y = gelu_f((X[(size_t)r * C + c] - mean) * inv);
    Yb[(size_t)r * C + c] = f2bf(y);
    s += y; mx = fmaxf(mx, y);
  }
  if (psum) {
    unsigned b = __float_as_uint(mx);
    unsigned enc = (b & 0x80000000u) ? ~b : (b | 0x80000000u);
    atomicAdd(&psum[c], s);
    atomicMax(&pmax[c], enc);
  }
}

// ---------------------------------------------------------------- CSR build
__global__ void edge_count(const int* __restrict__ ei, int* __restrict__ counts) {
  int e = blockIdx.x * blockDim.x + threadIdx.x;
  if (e >= E_TOT) return;
  int dst = (e < N_EDGES) ? ei[N_EDGES + e] : (e - N_EDGES);
  atomicAdd(&counts[dst], 1);
}

__global__ __launch_bounds__(1024) void scan_kernel(const int* __restrict__ counts,
                                                    int* __restrict__ indptr)
{
  __shared__ int sh[1024];
  int t = threadIdx.x;
  const int chunk = (N_NODES + 1023) / 1024;
  int start = t * chunk, end = min(start + chunk, N_NODES);
  int sum = 0;
  for (int i = start; i < end; i++) sum += counts[i];
  sh[t] = sum;
  __syncthreads();
  for (int off = 1; off < 1024; off <<= 1) {
    int v = (t >= off) ? sh[t - off] : 0;
    __syncthreads();
    sh[t] += v;
    __syncthreads();
  }
  int run = (t > 0) ? sh[t - 1] : 0;
  for (int i = start; i < end; i++) { indptr[i] = run; run += counts[i]; }
  if (t == 1023) indptr[N_NODES] = run;
}

__global__ void edge_fill(const int* __restrict__ ei, const int* __restrict__ indptr,
                          int* __restrict__ cursor, int* __restrict__ col)
{
  int e = blockIdx.x * blockDim.x + threadIdx.x;
  if (e >= E_TOT) return;
  int src, dst;
  if (e < N_EDGES) { src = ei[e]; dst = ei[N_EDGES + e]; }
  else             { src = dst = e - N_EDGES; }
  int pos = indptr[dst] + atomicAdd(&cursor[dst], 1);
  col[pos] = src;
}

// ---------------------------------------------------------------- GAT aggregation
// xlr bf16 [N,512]=[xl|xr]. Wave per node; 4 edges per online-softmax step,
// branch-free pad via col[e0], all static indices (rule #20).
// SOFTWARE-PIPELINED: next batch's gathers (LOAD4) issue before the current
// batch's shuffle-reduce (UPD4) — loads don't depend on softmax state.
// Math identical to the 560-us round-11 build (same batches, same order).
#define LOAD4(P, X, EB)                                              \
  _Pragma("unroll")                                                  \
  for (int b = 0; b < 4; b++) {                                      \
    bool valid = ((EB) + b) < e1;                                    \
    int j = col[valid ? (EB) + b : e0];                              \
    short4 xl4 = *(const short4*)(xlr + (size_t)j * NW + lane * 4);  \
    float pp = 0.f;                                                  \
    _Pragma("unroll")                                                \
    for (int k = 0; k < 4; k++) {                                    \
      X[b][k] = bf2f(((short*)&xl4)[k]);                             \
      float h = X[b][k] + xri[k];                                    \
      float lr = h > 0.f ? h : 0.2f * h;                             \
      pp += lr * attc[k];                                            \
    }                                                                \
    P[b] = valid ? pp : -INFINITY;                                   \
  }

#define UPD4(P, X)                                                   \
  {                                                                  \
    _Pragma("unroll")                                                \
    for (int off = 32; off; off >>= 1) {                             \
      _Pragma("unroll")                                              \
      for (int b = 0; b < 4; b++) P[b] += __shfl_xor(P[b], off);     \
    }                                                                \
    float mn = fmaxf(m, fmaxf(fmaxf(P[0], P[1]), fmaxf(P[2], P[3])));\
    float scale = __expf(m - mn);                                    \
    float w[4];                                                      \
    _Pragma("unroll")                                                \
    for (int b = 0; b < 4; b++) w[b] = __expf(P[b] - mn);            \
    s = s * scale + w[0] + w[1] + w[2] + w[3];                       \
    _Pragma("unroll")                                                \
    for (int k = 0; k < 4; k++)                                      \
      o[k] = o[k] * scale + w[0] * X[0][k] + w[1] * X[1][k]          \
                          + w[2] * X[2][k] + w[3] * X[3][k];         \
    m = mn;                                                          \
  }

__global__ __launch_bounds__(256) void gat_agg(
    const short* __restrict__ xlr,
    const int* __restrict__ indptr, const int* __restrict__ col,
    const float* __restrict__ att, const float* __restrict__ bias,
    float* __restrict__ out)
{
  int wave = threadIdx.x >> 6, lane = threadIdx.x & 63;
  int node = blockIdx.x * 4 + wave;
  if (node >= N_NODES) return;
  float attc[4], xri[4], o[4] = {0, 0, 0, 0};
  {
    short4 xr4 = *(const short4*)(xlr + (size_t)node * NW + HID + lane * 4);
    #pragma unroll
    for (int k = 0; k < 4; k++) {
      attc[k] = att[lane * 4 + k];
      xri[k] = bf2f(((short*)&xr4)[k]);
    }
  }
  float m = -INFINITY, s = 0.f;
  int e0 = indptr[node], e1 = indptr[node + 1];
  float pA[4], xA[4][4], pB[4], xB[4][4];
  LOAD4(pA, xA, e0);
  for (int e = e0; e < e1; e += 8) {
    LOAD4(pB, xB, e + 4);          // issued before A's reduce (overlap)
    UPD4(pA, xA);
    if (e + 8 < e1) LOAD4(pA, xA, e + 8);   // wave-uniform guard
    UPD4(pB, xB);                  // all-pad batch is an exact no-op
  }
  float inv = 1.0f / (s + 1e-16f);
  f32x4 ov;
  #pragma unroll
  for (int k = 0; k < 4; k++) ov[k] = o[k] * inv + bias[lane * 4 + k];
  *(f32x4*)(out + (size_t)node * HID + lane * 4) = ov;
}

// ---------------------------------------------------------------- late stage
__device__ __forceinline__ float fdec(unsigned u) {
  unsigned b = (u & 0x80000000u) ? (u & 0x7FFFFFFFu) : ~u;
  return __uint_as_float(b);
}

__global__ void build_xlate(const float* __restrict__ cfg, const float* __restrict__ cmean,
                            const float* __restrict__ cstd, const float* __restrict__ psum,
                            const unsigned* __restrict__ pmax, short* __restrict__ xlateb)
{
  int i = blockIdx.x * blockDim.x + threadIdx.x;
  if (i >= N_CFG * K288) return;
  int r = i / K288, c = i % K288;
  float v;
  if (c < CFG_FEAT) v = (cfg[r * CFG_FEAT + c] - cmean[c]) / (cstd[c] + 1e-4f);
  else if (c < CFG_FEAT + HID) {
    int p = c - CFG_FEAT;
    v = psum[p] * (1.0f / N_NODES) + fdec(pmax[p]);
  } else v = 0.f;
  xlateb[i] = f2bf(v);
}

// pred with fused final norm+gelu (stats from L2 GEMM epilogue)
__global__ __launch_bounds__(64) void pred_kernel(
    const float* __restrict__ h2, const float* __restrict__ stats,
    const float* __restrict__ W, const float* __restrict__ b,
    float* __restrict__ out)
{
  int r = blockIdx.x, lane = threadIdx.x;
  const float invM = 1.0f / (float)N_CFG;
  float v = 0.f;
  #pragma unroll
  for (int t = 0; t < 2; t++) {
    int c = lane + 64 * t;
    float mean = stats[c] * invM;
    float var = stats[128 + c] * invM - mean * mean;
    float y = gelu_f((h2[(size_t)r * 128 + c] - mean) * rsqrtf(var + 1e-5f));
    v += y * W[c];
  }
  #pragma unroll
  for (int off = 32; off; off >>= 1) v += __shfl_xor(v, off);
  if (lane == 0) out[r] = v + b[0];
}

// ================================================================ launch
extern "C" void kernel_launch(void* const* d_in, const int* in_sizes, int n_in,
                              void* d_out, int out_size, void* d_ws, size_t ws_size,
                              hipStream_t stream)
{
  const float* node_feat   = (const float*)d_in[0];
  const float* config_feat = (const float*)d_in[1];
  const float* nf_mean     = (const float*)d_in[2];
  const float* nf_std      = (const float*)d_in[3];
  const float* cf_mean     = (const float*)d_in[4];
  const float* cf_std      = (const float*)d_in[5];
  const float* emb_table   = (const float*)d_in[6];
  const float* early_W1    = (const float*)d_in[7];
  const float* early_W2    = (const float*)d_in[8];
  const float* gat_Wl      = (const float*)d_in[9];
  const float* gat_bl      = (const float*)d_in[10];
  const float* gat_Wr      = (const float*)d_in[11];
  const float* gat_br      = (const float*)d_in[12];
  const float* gat_att     = (const float*)d_in[13];
  const float* gat_bias    = (const float*)d_in[14];
  const float* late_W1     = (const float*)d_in[15];
  const float* late_W2     = (const float*)d_in[16];
  const float* pred_W      = (const float*)d_in[17];
  const float* pred_b      = (const float*)d_in[18];
  const int*   node_opcode = (const int*)d_in[19];
  const int*   edge_index  = (const int*)d_in[20];
  float* out = (float*)d_out;
  (void)in_sizes; (void)n_in; (void)out_size; (void)ws_size;

  char* ws = (char*)d_ws;
  size_t off = 0;
  auto alloc = [&](size_t bytes) -> void* {
    void* p = ws + off;
    off += (bytes + 255) & ~255ull;
    return p;
  };
  short* x268b = (short*)alloc((size_t)MPAD * K288 * 2);
  float* bufB  = (float*)alloc((size_t)N_NODES * HID * 4);
  short* bufAb = (short*)alloc((size_t)MPAD * HID * 2);
  short* xlr   = (short*)alloc((size_t)N_NODES * NW * 2);
  int* indptr  = (int*)alloc((N_NODES + 1) * 4);
  int* colidx  = (int*)alloc((size_t)E_TOT * 4);
  short* xlateb = (short*)alloc((size_t)1024 * K288 * 2);
  float* h1    = (float*)alloc((size_t)N_CFG * HID * 4);
  short* h1b   = (short*)alloc((size_t)1024 * HID * 2);
  float* h2    = (float*)alloc((size_t)N_CFG * 128 * 4);
  short* W1t   = (short*)alloc((size_t)HID * K288 * 2);
  short* W2t   = (short*)alloc((size_t)HID * HID * 2);
  short* Wlrt  = (short*)alloc((size_t)4 * NW * HID * 2);
  float* blr   = (float*)alloc(4 * NW * 4);
  short* lW1t  = (short*)alloc((size_t)HID * K288 * 2);
  short* lW2t  = (short*)alloc((size_t)128 * HID * 2);

  // ---- contiguous zero region (single memset per call) ----
  float* zbase = (float*)alloc((8 * 1024 + 512 + 2 * N_NODES) * 4);
  float* stats8 = zbase;
  float* psum   = zbase + 8192;
  unsigned* pmax = (unsigned*)(zbase + 8192 + 256);
  int* counts   = (int*)(zbase + 8192 + 512);
  int* cursor   = counts + N_NODES;
  const size_t zbytes = (8 * 1024 + 512 + 2 * N_NODES) * 4;
  auto slot = [&](int s) { return stats8 + s * 1024; };
  // slots: 0=E1 1=E2 2..5=G0..G3 6=L1 7=L2

  auto run_gemm = [&](int BM, const short* A, const short* Wt, const float* bias, float* C,
                      short* Cb, float* stats, int M, int N, int Kpad) {
    if (BM == 128) {
      dim3 grid((M + 127) / 128, N / 128);
      hipLaunchKernelGGL((gemm_mfma<128, 128>), grid, dim3(256), 0, stream,
                         A, Wt, bias, C, Cb, stats, M, N, Kpad);
    } else {
      dim3 grid((M + 63) / 64, N / 64);
      hipLaunchKernelGGL((gemm_mfma<64, 64>), grid, dim3(256), 0, stream,
                         A, Wt, bias, C, Cb, stats, M, N, Kpad);
    }
  };
  auto run_norm = [&](const float* X, short* Yb, int M, int C, float* stats,
                      float* ps, unsigned* pm) {
    hipLaunchKernelGGL(norm_gelu_col, dim3((M + 31) / 32), dim3(C), 0, stream,
                       X, Yb, M, C, stats, ps, pm);
  };

  hipMemsetAsync(zbase, 0, zbytes, stream);

  // weight prep (one kernel)
  {
    int total = HID * K288 + HID * HID + HID * K288 + 128 * HID + 4 * NW * HID + 4 * NW;
    hipLaunchKernelGGL(prep_weights, dim3((total + 255) / 256), dim3(256), 0, stream,
                       early_W1, early_W2, late_W1, late_W2, gat_Wl, gat_Wr, gat_bl, gat_br,
                       W1t, W2t, lW1t, lW2t, Wlrt, blr);
  }

  // CSR build
  hipLaunchKernelGGL(edge_count, dim3((E_TOT + 255) / 256), dim3(256), 0, stream,
                     edge_index, counts);
  hipLaunchKernelGGL(scan_kernel, dim3(1), dim3(1024), 0, stream, counts, indptr);
  hipLaunchKernelGGL(edge_fill, dim3((E_TOT + 255) / 256), dim3(256), 0, stream,
                     edge_index, indptr, cursor, colidx);

  // prep + early MLP
  hipLaunchKernelGGL(prep_kernel, dim3((N_NODES + 3) / 4), dim3(256), 0, stream,
                     node_feat, nf_mean, nf_std, emb_table, node_opcode, x268b);
  run_gemm(64, x268b, W1t, nullptr, bufB, nullptr, slot(0), N_NODES, HID, K288);
  run_norm(bufB, bufAb, N_NODES, HID, slot(0), nullptr, nullptr);
  run_gemm(64, bufAb, W2t, nullptr, bufB, nullptr, slot(1), N_NODES, HID, HID);
  run_norm(bufB, bufAb, N_NODES, HID, slot(1), nullptr, nullptr);

  // 4 GAT layers
  for (int l = 0; l < 4; l++) {
    run_gemm(128, bufAb, Wlrt + (size_t)l * NW * HID, blr + l * NW, nullptr, xlr, nullptr,
             N_NODES, NW, HID);
    hipLaunchKernelGGL(gat_agg, dim3((N_NODES + 3) / 4), dim3(256), 0, stream,
                       xlr, indptr, colidx, gat_att + l * HID, gat_bias + l * HID, bufB);
    hipLaunchKernelGGL(colstats, dim3((N_NODES + 63) / 64), dim3(HID), 0, stream,
                       bufB, N_NODES, HID, slot(2 + l));
    run_norm(bufB, bufAb, N_NODES, HID, slot(2 + l),
             (l == 3) ? psum : nullptr, (l == 3) ? pmax : nullptr);
  }

  // late MLP
  hipLaunchKernelGGL(build_xlate, dim3((N_CFG * K288 + 255) / 256), dim3(256), 0, stream,
                     config_feat, cf_mean, cf_std, psum, pmax, xlateb);
  run_gemm(64, xlateb, lW1t, nullptr, h1, nullptr, slot(6), N_CFG, HID, K288);
  run_norm(h1, h1b, N_CFG, HID, slot(6), nullptr, nullptr);
  run_gemm(64, h1b, lW2t, nullptr, h2, nullptr, slot(7), N_CFG, 128, HID);
  hipLaunchKernelGGL(pred_kernel, dim3(N_CFG), dim3(64), 0, stream,
                     h2, slot(7), pred_W, pred_b, out);
}

// Round 15
// 560.574 us; speedup vs baseline: 1.2954x; 1.0492x over previous
//
#include <hip/hip_runtime.h>
#include <math.h>

#define N_NODES 20000
#define N_EDGES 160000
#define N_CFG   1000
#define OP_FEAT 140
#define CFG_FEAT 24
#define HID     256
#define EMB     128
#define E_TOT   (N_EDGES + N_NODES)
#define K288    288          // 268 and 280 padded to multiple of 32
#define MPAD    20096        // 157 * 128
#define NW      512          // fused Wl|Wr output width

typedef __attribute__((ext_vector_type(8))) short short8v;
typedef __attribute__((ext_vector_type(4))) float f32x4;

__device__ __forceinline__ short f2bf(float f) {
  unsigned u = __float_as_uint(f);
  unsigned r = (u + 0x7FFFu + ((u >> 16) & 1u)) >> 16;
  return (short)r;
}
__device__ __forceinline__ float bf2f(short s) {
  return __uint_as_float(((unsigned)(unsigned short)s) << 16);
}
__device__ __forceinline__ float gelu_f(float x) {
  return 0.5f * x * (1.0f + erff(x * 0.70710678118654752f));
}

#define GLOAD_LDS(gptr, lptr) __builtin_amdgcn_global_load_lds( \
    (const __attribute__((address_space(1))) void*)(gptr),      \
    (__attribute__((address_space(3))) void*)(lptr), 16, 0, 0)

// ---------------------------------------------------------------- weight prep (merged)
__global__ void prep_weights(
    const float* __restrict__ eW1, const float* __restrict__ eW2,
    const float* __restrict__ lW1, const float* __restrict__ lW2,
    const float* __restrict__ Wl, const float* __restrict__ Wr,
    const float* __restrict__ bl, const float* __restrict__ br,
    short* __restrict__ W1t, short* __restrict__ W2t,
    short* __restrict__ lW1t, short* __restrict__ lW2t,
    short* __restrict__ Wlrt, float* __restrict__ blr)
{
  int i = blockIdx.x * 256 + threadIdx.x;
  const int s1 = HID * K288;      // W1t  [256][288]
  const int s2 = HID * HID;       // W2t  [256][256]
  const int s3 = HID * K288;      // lW1t [256][288]
  const int s4 = 128 * HID;       // lW2t [128][256]
  const int s5 = 4 * NW * HID;    // Wlrt [4][512][256]
  const int s6 = 4 * NW;          // blr
  if (i < s1) { int n = i / K288, k = i % K288;
    W1t[i] = (k < EMB + OP_FEAT) ? f2bf(eW1[(size_t)k * HID + n]) : (short)0; return; }
  i -= s1;
  if (i < s2) { int n = i >> 8, k = i & 255;
    W2t[i] = f2bf(eW2[(size_t)k * HID + n]); return; }
  i -= s2;
  if (i < s3) { int n = i / K288, k = i % K288;
    lW1t[i] = (k < CFG_FEAT + HID) ? f2bf(lW1[(size_t)k * HID + n]) : (short)0; return; }
  i -= s3;
  if (i < s4) { int n = i >> 8, k = i & 255;
    lW2t[i] = f2bf(lW2[(size_t)k * 128 + n]); return; }
  i -= s4;
  if (i < s5) { int l = i >> 17, rem = i & 131071, n = rem >> 8, k = rem & 255;
    float v = (n < HID) ? Wl[(size_t)l * HID * HID + (size_t)k * HID + n]
                        : Wr[(size_t)l * HID * HID + (size_t)k * HID + (n - HID)];
    Wlrt[i] = f2bf(v); return; }
  i -= s5;
  if (i < s6) { int l = i >> 9, j = i & 511;
    blr[i] = (j < HID) ? bl[l * HID + j] : br[l * HID + j - HID]; }
}

// ---------------------------------------------------------------- prep
__global__ __launch_bounds__(256) void prep_kernel(
    const float* __restrict__ node_feat, const float* __restrict__ nf_mean,
    const float* __restrict__ nf_std, const float* __restrict__ emb_table,
    const int* __restrict__ opcode, short* __restrict__ x268b)
{
  int wave = threadIdx.x >> 6;
  int lane = threadIdx.x & 63;
  int row = blockIdx.x * 4 + wave;
  if (row >= N_NODES) return;
  int op = opcode[row];
  float t0 = emb_table[op * EMB + lane];
  float t1 = emb_table[op * EMB + 64 + lane];
  float ss = t0 * t0 + t1 * t1;
  #pragma unroll
  for (int off = 32; off; off >>= 1) ss += __shfl_xor(ss, off);
  float sc = fminf(1.0f, 1.0f / (sqrtf(ss) + 1e-7f));
  short* dst = x268b + (size_t)row * K288;
  dst[lane] = f2bf(t0 * sc);
  dst[64 + lane] = f2bf(t1 * sc);
  for (int k = lane; k < OP_FEAT; k += 64)
    dst[EMB + k] = f2bf((node_feat[(size_t)row * OP_FEAT + k] - nf_mean[k]) / (nf_std[k] + 1e-4f));
  if (lane < K288 - EMB - OP_FEAT) dst[EMB + OP_FEAT + lane] = 0;
}

// ---------------------------------------------------------------- MFMA GEMM (2-phase, BK=32)
// 128x128 (4 waves 2x2 of 64x64) or 64x64 (4 waves 2x2 of 32x32).
template<int BM, int BN>
__global__ __launch_bounds__(256) void gemm_mfma(
    const short* __restrict__ A, const short* __restrict__ Wt,
    const float* __restrict__ bias, float* __restrict__ C,
    short* __restrict__ Cb, float* __restrict__ stats,
    int M, int N, int Kpad)
{
  constexpr int MI = (BM == 128) ? 4 : 2;
  constexpr int NI = (BN == 128) ? 4 : 2;
  __shared__ __align__(16) short As[2][4][BM][8];
  __shared__ __align__(16) short Bs[2][4][BN][8];
  int tid = threadIdx.x;
  int wave = tid >> 6, lane = tid & 63;
  int bm = blockIdx.x * BM, bn = blockIdx.y * BN;
  int wr = (BM == 128) ? (wave >> 1) * 64 : (wave >> 1) * 32;
  int wc = (BM == 128) ? (wave & 1) * 64 : (wave & 1) * 32;
  int g = lane >> 4, r16 = lane & 15;
  f32x4 acc[MI][NI] = {};
  int nt = Kpad >> 5;

  auto STAGE = [&](int t, int b) {
    int k0 = t * 32;
    if constexpr (BM == 128) {
      #pragma unroll
      for (int s2 = 0; s2 < 2; s2++) {
        int s = wave * 2 + s2;
        int sg = s >> 1, r0 = (s & 1) * 64;
        GLOAD_LDS(A  + (size_t)(bm + r0 + lane) * Kpad + k0 + sg * 8, &As[b][sg][r0][0]);
        GLOAD_LDS(Wt + (size_t)(bn + r0 + lane) * Kpad + k0 + sg * 8, &Bs[b][sg][r0][0]);
      }
    } else {
      // 64x64: one A-load + one B-load per thread stages the full tile
      GLOAD_LDS(A  + (size_t)(bm + lane) * Kpad + k0 + wave * 8, &As[b][wave][0][0]);
      GLOAD_LDS(Wt + (size_t)(bn + lane) * Kpad + k0 + wave * 8, &Bs[b][wave][0][0]);
    }
  };

  STAGE(0, 0);
  for (int t = 0; t < nt; t++) {
    int b = t & 1;
    __syncthreads();                 // buf b ready (vmcnt drained at barrier)
    if (t + 1 < nt) STAGE(t + 1, b ^ 1);
    short8v af[MI], bfv[NI];
    #pragma unroll
    for (int mi = 0; mi < MI; mi++)
      af[mi] = *(const short8v*)&As[b][g][wr + mi * 16 + r16][0];
    #pragma unroll
    for (int ni = 0; ni < NI; ni++)
      bfv[ni] = *(const short8v*)&Bs[b][g][wc + ni * 16 + r16][0];
    #pragma unroll
    for (int mi = 0; mi < MI; mi++)
      #pragma unroll
      for (int ni = 0; ni < NI; ni++)
        acc[mi][ni] = __builtin_amdgcn_mfma_f32_16x16x32_bf16(af[mi], bfv[ni], acc[mi][ni], 0, 0, 0);
  }

  int rg = lane >> 4;
  #pragma unroll
  for (int ni = 0; ni < NI; ni++) {
    int gc = bn + wc + ni * 16 + r16;
    float bv = bias ? bias[gc] : 0.f;
    float s = 0.f, sq = 0.f;
    #pragma unroll
    for (int mi = 0; mi < MI; mi++) {
      #pragma unroll
      for (int r = 0; r < 4; r++) {
        int gr = bm + wr + mi * 16 + rg * 4 + r;
        if (gr < M) {
          float v = acc[mi][ni][r] + bv;
          if (C)  C[(size_t)gr * N + gc] = v;
          if (Cb) Cb[(size_t)gr * N + gc] = f2bf(v);
          s += v; sq += v * v;
        }
      }
    }
    if (stats) {
      s  += __shfl_xor(s, 16);  sq += __shfl_xor(sq, 16);
      s  += __shfl_xor(s, 32);  sq += __shfl_xor(sq, 32);
      if (rg == 0) { atomicAdd(&stats[gc], s); atomicAdd(&stats[N + gc], sq); }
    }
  }
}

// ---------------------------------------------------------------- column stats
__global__ void colstats(const float* __restrict__ X, int M, int C,
                         float* __restrict__ stats)
{
  int c = threadIdx.x;
  int r0 = blockIdx.x * 64;
  int r1 = min(r0 + 64, M);
  float s = 0.f, sq = 0.f;
  for (int r = r0; r < r1; r++) {
    float v = X[(size_t)r * C + c];
    s += v; sq += v * v;
  }
  atomicAdd(&stats[c], s);
  atomicAdd(&stats[C + c], sq);
}

// ---------------------------------------------------------------- norm + gelu (column-major)
__global__ void norm_gelu_col(const float* __restrict__ X, short* __restrict__ Yb,
                              int M, int C, const float* __restrict__ stats,
                              float* __restrict__ psum, unsigned* __restrict__ pmax)
{
  int c = threadIdx.x;
  int r0 = blockIdx.x * 32, r1 = min(r0 + 32, M);
  float invM = 1.0f / (float)M;
  float mean = stats[c] * invM;
  float var = stats[C + c] * invM - mean * mean;
  float inv = rsqrtf(var + 1e-5f);
  float s = 0.f, mx = -INFINITY;
  for (int r = r0; r < r1; r++) {
    float y = gelu_f((X[(size_t)r * C + c] - mean) * inv);
    Yb[(size_t)r * C + c] = f2bf(y);
    s += y; mx = fmaxf(mx, y);
  }
  if (psum) {
    unsigned b = __float_as_uint(mx);
    unsigned enc = (b & 0x80000000u) ? ~b : (b | 0x80000000u);
    atomicAdd(&psum[c], s);
    atomicMax(&pmax[c], enc);
  }
}

// ---------------------------------------------------------------- CSR build
__global__ void edge_count(const int* __restrict__ ei, int* __restrict__ counts) {
  int e = blockIdx.x * blockDim.x + threadIdx.x;
  if (e >= E_TOT) return;
  int dst = (e < N_EDGES) ? ei[N_EDGES + e] : (e - N_EDGES);
  atomicAdd(&counts[dst], 1);
}

__global__ __launch_bounds__(1024) void scan_kernel(const int* __restrict__ counts,
                                                    int* __restrict__ indptr)
{
  __shared__ int sh[1024];
  int t = threadIdx.x;
  const int chunk = (N_NODES + 1023) / 1024;
  int start = t * chunk, end = min(start + chunk, N_NODES);
  int sum = 0;
  for (int i = start; i < end; i++) sum += counts[i];
  sh[t] = sum;
  __syncthreads();
  for (int off = 1; off < 1024; off <<= 1) {
    int v = (t >= off) ? sh[t - off] : 0;
    __syncthreads();
    sh[t] += v;
    __syncthreads();
  }
  int run = (t > 0) ? sh[t - 1] : 0;
  for (int i = start; i < end; i++) { indptr[i] = run; run += counts[i]; }
  if (t == 1023) indptr[N_NODES] = run;
}

__global__ void edge_fill(const int* __restrict__ ei, const int* __restrict__ indptr,
                          int* __restrict__ cursor, int* __restrict__ col)
{
  int e = blockIdx.x * blockDim.x + threadIdx.x;
  if (e >= E_TOT) return;
  int src, dst;
  if (e < N_EDGES) { src = ei[e]; dst = ei[N_EDGES + e]; }
  else             { src = dst = e - N_EDGES; }
  int pos = indptr[dst] + atomicAdd(&cursor[dst], 1);
  col[pos] = src;
}

// ---------------------------------------------------------------- GAT aggregation
// (the 560-us round-11 version) xlr bf16 [N,512]=[xl|xr]. Wave per node; 4 edges
// per online-softmax step, branch-free pad via col[e0], all static indices.
__global__ __launch_bounds__(256) void gat_agg(
    const short* __restrict__ xlr,
    const int* __restrict__ indptr, const int* __restrict__ col,
    const float* __restrict__ att, const float* __restrict__ bias,
    float* __restrict__ out)
{
  int wave = threadIdx.x >> 6, lane = threadIdx.x & 63;
  int node = blockIdx.x * 4 + wave;
  if (node >= N_NODES) return;
  float attc[4], xri[4], o[4] = {0, 0, 0, 0};
  {
    short4 xr4 = *(const short4*)(xlr + (size_t)node * NW + HID + lane * 4);
    #pragma unroll
    for (int k = 0; k < 4; k++) {
      attc[k] = att[lane * 4 + k];
      xri[k] = bf2f(((short*)&xr4)[k]);
    }
  }
  float m = -INFINITY, s = 0.f;
  int e0 = indptr[node], e1 = indptr[node + 1];
  for (int e = e0; e < e1; e += 4) {
    float p[4];
    float xlj[4][4];
    #pragma unroll
    for (int b = 0; b < 4; b++) {
      bool valid = (e + b) < e1;
      int j = col[valid ? e + b : e0];     // e0 always valid (self-loop)
      short4 xl4 = *(const short4*)(xlr + (size_t)j * NW + lane * 4);
      float pp = 0.f;
      #pragma unroll
      for (int k = 0; k < 4; k++) {
        xlj[b][k] = bf2f(((short*)&xl4)[k]);
        float h = xlj[b][k] + xri[k];
        float lr = h > 0.f ? h : 0.2f * h;
        pp += lr * attc[k];
      }
      p[b] = valid ? pp : -INFINITY;
    }
    #pragma unroll
    for (int off = 32; off; off >>= 1) {
      #pragma unroll
      for (int b = 0; b < 4; b++) p[b] += __shfl_xor(p[b], off);
    }
    float mn = fmaxf(m, fmaxf(fmaxf(p[0], p[1]), fmaxf(p[2], p[3])));
    float scale = __expf(m - mn);
    float w[4];
    #pragma unroll
    for (int b = 0; b < 4; b++) w[b] = __expf(p[b] - mn);
    s = s * scale + w[0] + w[1] + w[2] + w[3];
    #pragma unroll
    for (int k = 0; k < 4; k++)
      o[k] = o[k] * scale + w[0] * xlj[0][k] + w[1] * xlj[1][k]
                          + w[2] * xlj[2][k] + w[3] * xlj[3][k];
    m = mn;
  }
  float inv = 1.0f / (s + 1e-16f);
  f32x4 ov;
  #pragma unroll
  for (int k = 0; k < 4; k++) ov[k] = o[k] * inv + bias[lane * 4 + k];
  *(f32x4*)(out + (size_t)node * HID + lane * 4) = ov;
}

// ---------------------------------------------------------------- late stage
__device__ __forceinline__ float fdec(unsigned u) {
  unsigned b = (u & 0x80000000u) ? (u & 0x7FFFFFFFu) : ~u;
  return __uint_as_float(b);
}

__global__ void build_xlate(const float* __restrict__ cfg, const float* __restrict__ cmean,
                            const float* __restrict__ cstd, const float* __restrict__ psum,
                            const unsigned* __restrict__ pmax, short* __restrict__ xlateb)
{
  int i = blockIdx.x * blockDim.x + threadIdx.x;
  if (i >= N_CFG * K288) return;
  int r = i / K288, c = i % K288;
  float v;
  if (c < CFG_FEAT) v = (cfg[r * CFG_FEAT + c] - cmean[c]) / (cstd[c] + 1e-4f);
  else if (c < CFG_FEAT + HID) {
    int p = c - CFG_FEAT;
    v = psum[p] * (1.0f / N_NODES) + fdec(pmax[p]);
  } else v = 0.f;
  xlateb[i] = f2bf(v);
}

// pred with fused final norm+gelu (stats from L2 GEMM epilogue)
__global__ __launch_bounds__(64) void pred_kernel(
    const float* __restrict__ h2, const float* __restrict__ stats,
    const float* __restrict__ W, const float* __restrict__ b,
    float* __restrict__ out)
{
  int r = blockIdx.x, lane = threadIdx.x;
  const float invM = 1.0f / (float)N_CFG;
  float v = 0.f;
  #pragma unroll
  for (int t = 0; t < 2; t++) {
    int c = lane + 64 * t;
    float mean = stats[c] * invM;
    float var = stats[128 + c] * invM - mean * mean;
    float y = gelu_f((h2[(size_t)r * 128 + c] - mean) * rsqrtf(var + 1e-5f));
    v += y * W[c];
  }
  #pragma unroll
  for (int off = 32; off; off >>= 1) v += __shfl_xor(v, off);
  if (lane == 0) out[r] = v + b[0];
}

// ================================================================ launch
extern "C" void kernel_launch(void* const* d_in, const int* in_sizes, int n_in,
                              void* d_out, int out_size, void* d_ws, size_t ws_size,
                              hipStream_t stream)
{
  const float* node_feat   = (const float*)d_in[0];
  const float* config_feat = (const float*)d_in[1];
  const float* nf_mean     = (const float*)d_in[2];
  const float* nf_std      = (const float*)d_in[3];
  const float* cf_mean     = (const float*)d_in[4];
  const float* cf_std      = (const float*)d_in[5];
  const float* emb_table   = (const float*)d_in[6];
  const float* early_W1    = (const float*)d_in[7];
  const float* early_W2    = (const float*)d_in[8];
  const float* gat_Wl      = (const float*)d_in[9];
  const float* gat_bl      = (const float*)d_in[10];
  const float* gat_Wr      = (const float*)d_in[11];
  const float* gat_br      = (const float*)d_in[12];
  const float* gat_att     = (const float*)d_in[13];
  const float* gat_bias    = (const float*)d_in[14];
  const float* late_W1     = (const float*)d_in[15];
  const float* late_W2     = (const float*)d_in[16];
  const float* pred_W      = (const float*)d_in[17];
  const float* pred_b      = (const float*)d_in[18];
  const int*   node_opcode = (const int*)d_in[19];
  const int*   edge_index  = (const int*)d_in[20];
  float* out = (float*)d_out;
  (void)in_sizes; (void)n_in; (void)out_size; (void)ws_size;

  char* ws = (char*)d_ws;
  size_t off = 0;
  auto alloc = [&](size_t bytes) -> void* {
    void* p = ws + off;
    off += (bytes + 255) & ~255ull;
    return p;
  };
  short* x268b = (short*)alloc((size_t)MPAD * K288 * 2);
  float* bufB  = (float*)alloc((size_t)N_NODES * HID * 4);
  short* bufAb = (short*)alloc((size_t)MPAD * HID * 2);
  short* xlr   = (short*)alloc((size_t)N_NODES * NW * 2);
  int* indptr  = (int*)alloc((N_NODES + 1) * 4);
  int* colidx  = (int*)alloc((size_t)E_TOT * 4);
  short* xlateb = (short*)alloc((size_t)1024 * K288 * 2);
  float* h1    = (float*)alloc((size_t)N_CFG * HID * 4);
  short* h1b   = (short*)alloc((size_t)1024 * HID * 2);
  float* h2    = (float*)alloc((size_t)N_CFG * 128 * 4);
  short* W1t   = (short*)alloc((size_t)HID * K288 * 2);
  short* W2t   = (short*)alloc((size_t)HID * HID * 2);
  short* Wlrt  = (short*)alloc((size_t)4 * NW * HID * 2);
  float* blr   = (float*)alloc(4 * NW * 4);
  short* lW1t  = (short*)alloc((size_t)HID * K288 * 2);
  short* lW2t  = (short*)alloc((size_t)128 * HID * 2);

  // ---- contiguous zero region (single memset per call) ----
  float* zbase = (float*)alloc((8 * 1024 + 512 + 2 * N_NODES) * 4);
  float* stats8 = zbase;
  float* psum   = zbase + 8192;
  unsigned* pmax = (unsigned*)(zbase + 8192 + 256);
  int* counts   = (int*)(zbase + 8192 + 512);
  int* cursor   = counts + N_NODES;
  const size_t zbytes = (8 * 1024 + 512 + 2 * N_NODES) * 4;
  auto slot = [&](int s) { return stats8 + s * 1024; };
  // slots: 0=E1 1=E2 2..5=G0..G3 6=L1 7=L2

  auto run_gemm = [&](int BM, const short* A, const short* Wt, const float* bias, float* C,
                      short* Cb, float* stats, int M, int N, int Kpad) {
    if (BM == 128) {
      dim3 grid((M + 127) / 128, N / 128);
      hipLaunchKernelGGL((gemm_mfma<128, 128>), grid, dim3(256), 0, stream,
                         A, Wt, bias, C, Cb, stats, M, N, Kpad);
    } else {
      dim3 grid((M + 63) / 64, N / 64);
      hipLaunchKernelGGL((gemm_mfma<64, 64>), grid, dim3(256), 0, stream,
                         A, Wt, bias, C, Cb, stats, M, N, Kpad);
    }
  };
  auto run_norm = [&](const float* X, short* Yb, int M, int C, float* stats,
                      float* ps, unsigned* pm) {
    hipLaunchKernelGGL(norm_gelu_col, dim3((M + 31) / 32), dim3(C), 0, stream,
                       X, Yb, M, C, stats, ps, pm);
  };

  hipMemsetAsync(zbase, 0, zbytes, stream);

  // weight prep (one kernel)
  {
    int total = HID * K288 + HID * HID + HID * K288 + 128 * HID + 4 * NW * HID + 4 * NW;
    hipLaunchKernelGGL(prep_weights, dim3((total + 255) / 256), dim3(256), 0, stream,
                       early_W1, early_W2, late_W1, late_W2, gat_Wl, gat_Wr, gat_bl, gat_br,
                       W1t, W2t, lW1t, lW2t, Wlrt, blr);
  }

  // CSR build
  hipLaunchKernelGGL(edge_count, dim3((E_TOT + 255) / 256), dim3(256), 0, stream,
                     edge_index, counts);
  hipLaunchKernelGGL(scan_kernel, dim3(1), dim3(1024), 0, stream, counts, indptr);
  hipLaunchKernelGGL(edge_fill, dim3((E_TOT + 255) / 256), dim3(256), 0, stream,
                     edge_index, indptr, cursor, colidx);

  // prep + early MLP
  hipLaunchKernelGGL(prep_kernel, dim3((N_NODES + 3) / 4), dim3(256), 0, stream,
                     node_feat, nf_mean, nf_std, emb_table, node_opcode, x268b);
  run_gemm(64, x268b, W1t, nullptr, bufB, nullptr, slot(0), N_NODES, HID, K288);
  run_norm(bufB, bufAb, N_NODES, HID, slot(0), nullptr, nullptr);
  run_gemm(64, bufAb, W2t, nullptr, bufB, nullptr, slot(1), N_NODES, HID, HID);
  run_norm(bufB, bufAb, N_NODES, HID, slot(1), nullptr, nullptr);

  // 4 GAT layers
  for (int l = 0; l < 4; l++) {
    run_gemm(128, bufAb, Wlrt + (size_t)l * NW * HID, blr + l * NW, nullptr, xlr, nullptr,
             N_NODES, NW, HID);
    hipLaunchKernelGGL(gat_agg, dim3((N_NODES + 3) / 4), dim3(256), 0, stream,
                       xlr, indptr, colidx, gat_att + l * HID, gat_bias + l * HID, bufB);
    hipLaunchKernelGGL(colstats, dim3((N_NODES + 63) / 64), dim3(HID), 0, stream,
                       bufB, N_NODES, HID, slot(2 + l));
    run_norm(bufB, bufAb, N_NODES, HID, slot(2 + l),
             (l == 3) ? psum : nullptr, (l == 3) ? pmax : nullptr);
  }

  // late MLP
  hipLaunchKernelGGL(build_xlate, dim3((N_CFG * K288 + 255) / 256), dim3(256), 0, stream,
                     config_feat, cf_mean, cf_std, psum, pmax, xlateb);
  run_gemm(64, xlateb, lW1t, nullptr, h1, nullptr, slot(6), N_CFG, HID, K288);
  run_norm(h1, h1b, N_CFG, HID, slot(6), nullptr, nullptr);
  run_gemm(64, h1b, lW2t, nullptr, h2, nullptr, slot(7), N_CFG, 128, HID);
  hipLaunchKernelGGL(pred_kernel, dim3(N_CFG), dim3(64), 0, stream,
                     h2, slot(7), pred_W, pred_b, out);
}